// Round 16
// baseline (2061.052 us; speedup 1.0000x reference)
//
#include <hip/hip_runtime.h>

#define NN   50000
#define RR   500
#define MM   120000
#define EE   960000
#define NEE  800000
#define BB   8192
#define DD   200
#define HH1  256
#define HIDD 512
#define OCC  50

typedef unsigned int  u32;
typedef unsigned short u16;
typedef __attribute__((ext_vector_type(8))) short bf16x8;
typedef __attribute__((ext_vector_type(4))) float f32x4;

static __device__ __forceinline__ float bf2f(u16 u) {
    u32 x = ((u32)u) << 16;
    return __uint_as_float(x);
}
static __device__ __forceinline__ u16 f2bf(float f) {
    u32 x = __float_as_uint(f);
    u32 r = (x + 0x7FFFu + ((x >> 16) & 1u)) >> 16;
    return (u16)r;
}
static __device__ __forceinline__ u32 pack2(float a, float b) {
    return (u32)f2bf(a) | ((u32)f2bf(b) << 16);
}
static __device__ __forceinline__ void unpack2(u32 v, float& a, float& b) {
    a = bf2f((u16)(v & 0xFFFFu));
    b = bf2f((u16)(v >> 16));
}

static __device__ __forceinline__ float wredsum(float v) {
#pragma unroll
    for (int off = 32; off > 0; off >>= 1) v += __shfl_xor(v, off);
    return v;
}

static __device__ __forceinline__ u32 relu2bf(u32 x) {
    if (x & 0x00008000u) x &= 0xFFFF0000u;
    if (x & 0x80000000u) x &= 0x0000FFFFu;
    return x;
}
static __device__ __forceinline__ bf16x8 zero8() {
    bf16x8 z;
#pragma unroll
    for (int i = 0; i < 8; ++i) z[i] = 0;
    return z;
}

// ---------------- merged l2 normalize: rows<NN -> entb (bf16); rows>=NN -> relf+relb ----------------
__global__ void k_l2norm2(const float* __restrict__ ent_in, const float* __restrict__ rel_in,
                          u16* __restrict__ entb, float* __restrict__ relf,
                          u16* __restrict__ relb) {
    int w = (blockIdx.x * blockDim.x + threadIdx.x) >> 6;
    int lane = threadIdx.x & 63;
    if (w >= NN + RR) return;
    bool isent = w < NN;
    const float* r = isent ? (ent_in + (size_t)w * DD) : (rel_in + (size_t)(w - NN) * DD);
    float s = 0.f;
    for (int d = lane; d < DD; d += 64) { float v = r[d]; s += v * v; }
    s = wredsum(s);
    float inv = 1.0f / fmaxf(sqrtf(s), 1e-12f);
    for (int d = lane; d < DD; d += 64) {
        float v = r[d] * inv;
        if (isent) {
            entb[(size_t)w * DD + d] = f2bf(v);
        } else {
            relf[(size_t)(w - NN) * DD + d] = v;
            relb[(size_t)(w - NN) * DD + d] = f2bf(v);
        }
    }
}

__global__ void k_gather_perm(const int* __restrict__ bx, const int* __restrict__ perm,
                              int* __restrict__ idx1, int M) {
    int m = blockIdx.x * blockDim.x + threadIdx.x;
    if (m < M) idx1[m] = perm[bx[m]];
}

__global__ void k_edge_idx(const int* __restrict__ srcE, const int* __restrict__ map,
                           int* __restrict__ outE, int n) {
    int e = blockIdx.x * blockDim.x + threadIdx.x;
    if (e < n) outE[e] = map[srcE[e]];
}

// weight prep: split f32 [Kd][Nc] into transposed bf16 hi/lo planes [Nc][Kd]
__global__ void k_prepw(const float* __restrict__ src, int Nc, int Kd,
                        u16* __restrict__ hi, u16* __restrict__ lo) {
    int i = blockIdx.x * blockDim.x + threadIdx.x;
    if (i >= Nc * Kd) return;
    int n = i / Kd, k = i - n * Kd;
    float b = src[(size_t)k * Nc + n];
    u16 hb_ = f2bf(b);
    hi[i] = hb_;
    lo[i] = f2bf(b - bf2f(hb_));
}

// fused weight: W2bg = W2b[256,200] @ Wg[200,512] -> planes [512][256]
__global__ void k_fusew(const float* __restrict__ W2b, const float* __restrict__ Wg,
                        u16* __restrict__ hi, u16* __restrict__ lo) {
    int i = blockIdx.x * blockDim.x + threadIdx.x;
    if (i >= HIDD * HH1) return;
    int n = i >> 8, k = i & 255;
    float s = 0.f;
    for (int j = 0; j < DD; ++j) s += W2b[k * DD + j] * Wg[(size_t)j * HIDD + n];
    u16 h = f2bf(s);
    hi[i] = h;
    lo[i] = f2bf(s - bf2f(h));
}

// ---------------- CSR build ----------------
// merged histogram over three index arrays
__global__ void k_hist3(const int* __restrict__ i0, int* __restrict__ c0, int n0,
                        const int* __restrict__ i1, int* __restrict__ c1, int n1,
                        const int* __restrict__ i2, int* __restrict__ c2, int n2) {
    int i = blockIdx.x * blockDim.x + threadIdx.x;
    if (i < n0) { atomicAdd(&c0[i0[i]], 1); return; }
    i -= n0;
    if (i < n1) { atomicAdd(&c1[i1[i]], 1); return; }
    i -= n1;
    if (i < n2) atomicAdd(&c2[i2[i]], 1);
}

// three exclusive scans in one dispatch; also writes the cursor copy
__global__ __launch_bounds__(1024) void k_scan3(
    const int* __restrict__ in0, int* __restrict__ out0, int* __restrict__ cur0, int n0,
    const int* __restrict__ in1, int* __restrict__ out1, int* __restrict__ cur1, int n1,
    const int* __restrict__ in2, int* __restrict__ out2, int* __restrict__ cur2, int n2) {
    __shared__ int wtot[16];
    __shared__ int wexc[16];
    __shared__ int s_carry;
    const int* in = (blockIdx.x == 0) ? in0 : (blockIdx.x == 1) ? in1 : in2;
    int* out = (blockIdx.x == 0) ? out0 : (blockIdx.x == 1) ? out1 : out2;
    int* cur = (blockIdx.x == 0) ? cur0 : (blockIdx.x == 1) ? cur1 : cur2;
    int n = (blockIdx.x == 0) ? n0 : (blockIdx.x == 1) ? n1 : n2;
    int tid = threadIdx.x, lane = tid & 63, wid = tid >> 6;
    if (tid == 0) s_carry = 0;
    __syncthreads();
    for (int base = 0; base < n; base += 1024) {
        int i = base + tid;
        int v = (i < n) ? in[i] : 0;
        int x = v;
#pragma unroll
        for (int off = 1; off < 64; off <<= 1) {
            int t = __shfl_up(x, off);
            if (lane >= off) x += t;
        }
        if (lane == 63) wtot[wid] = x;
        __syncthreads();
        if (wid == 0) {
            int wv2 = (lane < 16) ? wtot[lane] : 0;
            int y = wv2;
#pragma unroll
            for (int off = 1; off < 16; off <<= 1) {
                int t = __shfl_up(y, off);
                if (lane >= off) y += t;
            }
            if (lane < 16) wexc[lane] = y - wv2;
            if (lane == 15) wtot[15] = y;
        }
        __syncthreads();
        if (i < n) {
            int ev = s_carry + wexc[wid] + (x - v);
            out[i] = ev;
            cur[i] = ev;
        }
        int chunk_total = wtot[15];
        __syncthreads();
        if (tid == 0) s_carry += chunk_total;
        __syncthreads();
    }
    if (threadIdx.x == 0) out[n] = s_carry;
}

__global__ void k_fill2(const int* __restrict__ dst, const int* __restrict__ src,
                        const float* __restrict__ w, int* __restrict__ cursor,
                        int* __restrict__ srcs_out, float* __restrict__ ws_out, int n) {
    int e = blockIdx.x * blockDim.x + threadIdx.x;
    if (e >= n) return;
    int p = atomicAdd(&cursor[dst[e]], 1);
    srcs_out[p] = src[e];
    ws_out[p] = w[e];
}

__global__ void k_fill1(const int* __restrict__ idx, int* __restrict__ cursor,
                        int* __restrict__ outm, int n) {
    int m = blockIdx.x * blockDim.x + threadIdx.x;
    if (m >= n) return;
    int p = atomicAdd(&cursor[idx[m]], 1);
    outm[p] = m;
}

// ---------------- fused MCE pull (8-edge MLP) ----------------
__global__ void k_pull_mce(const int* __restrict__ rp, const int* __restrict__ ivE,
                           const int* __restrict__ giE, const float* __restrict__ wE,
                           const u16* __restrict__ Pent, const u16* __restrict__ Prel,
                           u16* __restrict__ out, int ndst) {
    int wv = (blockIdx.x * blockDim.x + threadIdx.x) >> 6;
    if (wv >= ndst) return;
    int lane = threadIdx.x & 63;
    int beg = rp[wv], end = rp[wv + 1];
    float accA[2] = {0.f, 0.f}, accB[2] = {0.f, 0.f};
    int e = beg;
    for (; e + 8 <= end; e += 8) {
        const u32* pe[8];
        const u32* pr[8];
        float ws[8];
#pragma unroll
        for (int q = 0; q < 8; ++q) {
            pe[q] = (const u32*)(Pent + (size_t)ivE[e + q] * HH1);
            pr[q] = (const u32*)(Prel + (size_t)giE[e + q] * HH1);
            ws[q] = wE[e + q];
        }
        u32 vp[8][2], vr[8][2];
#pragma unroll
        for (int q = 0; q < 8; ++q)
#pragma unroll
            for (int t = 0; t < 2; ++t) {
                int p = lane + 64 * t;
                vp[q][t] = pe[q][p];
                vr[q][t] = pr[q][p];
            }
#pragma unroll
        for (int q = 0; q < 8; ++q)
#pragma unroll
            for (int t = 0; t < 2; ++t) {
                float a, b, c, d;
                unpack2(vp[q][t], a, b); unpack2(vr[q][t], c, d);
                accA[t] += (a + c) * ws[q]; accB[t] += (b + d) * ws[q];
            }
    }
    for (; e < end; ++e) {
        int iv = ivE[e], gi = giE[e];
        float w = wE[e];
        const u32* pe = (const u32*)(Pent + (size_t)iv * HH1);
        const u32* pr = (const u32*)(Prel + (size_t)gi * HH1);
#pragma unroll
        for (int t = 0; t < 2; ++t) {
            int p = lane + 64 * t;
            float a, b, c, d;
            unpack2(pe[p], a, b); unpack2(pr[p], c, d);
            accA[t] += (a + c) * w; accB[t] += (b + d) * w;
        }
    }
    u32* o = (u32*)(out + (size_t)wv * HH1);
#pragma unroll
    for (int t = 0; t < 2; ++t) o[lane + 64 * t] = pack2(accA[t], accB[t]);
}

// ---------------- CSR pull (8-edge MLP): INS/OUTS: 0 = bf16 plane, 1 = split pair ----------------
template<int DIMS, int INS, int OUTS>
__global__ void k_pull(const int* __restrict__ rp, const int* __restrict__ srcs,
                       const float* __restrict__ wsrt,
                       const u16* __restrict__ inh, const u16* __restrict__ inl,
                       u16* __restrict__ outh, u16* __restrict__ outl, int ndst) {
    int wv = (blockIdx.x * blockDim.x + threadIdx.x) >> 6;
    if (wv >= ndst) return;
    int lane = threadIdx.x & 63;
    int beg = rp[wv], end = rp[wv + 1];
    constexpr int NP = DIMS / 2;
    constexpr int NT = (NP + 63) / 64;
    float accA[NT], accB[NT];
#pragma unroll
    for (int t = 0; t < NT; ++t) { accA[t] = 0.f; accB[t] = 0.f; }
    int e = beg;
    for (; e + 8 <= end; e += 8) {
        const u32* rh[8];
        const u32* rl[8];
        float ws[8];
#pragma unroll
        for (int q = 0; q < 8; ++q) {
            int s = srcs[e + q];
            rh[q] = (const u32*)(inh + (size_t)s * DIMS);
            if (INS) rl[q] = (const u32*)(inl + (size_t)s * DIMS);
            ws[q] = wsrt[e + q];
        }
        u32 vh[8][NT], vl[8][NT];
#pragma unroll
        for (int q = 0; q < 8; ++q)
#pragma unroll
            for (int t = 0; t < NT; ++t) {
                int p = lane + 64 * t;
                if (p < NP) {
                    vh[q][t] = rh[q][p];
                    if (INS) vl[q][t] = rl[q][p];
                }
            }
#pragma unroll
        for (int q = 0; q < 8; ++q)
#pragma unroll
            for (int t = 0; t < NT; ++t) {
                int p = lane + 64 * t;
                if (p < NP) {
                    float a, b;
                    unpack2(vh[q][t], a, b);
                    if (INS) { float a2, b2; unpack2(vl[q][t], a2, b2); a += a2; b += b2; }
                    accA[t] += a * ws[q]; accB[t] += b * ws[q];
                }
            }
    }
    for (; e < end; ++e) {
        int s = srcs[e];
        float w = wsrt[e];
        const u32* rh = (const u32*)(inh + (size_t)s * DIMS);
        const u32* rl = INS ? (const u32*)(inl + (size_t)s * DIMS) : nullptr;
#pragma unroll
        for (int t = 0; t < NT; ++t) {
            int p = lane + 64 * t;
            if (p < NP) {
                float a, b;
                unpack2(rh[p], a, b);
                if (INS) { float a2, b2; unpack2(rl[p], a2, b2); a += a2; b += b2; }
                accA[t] += a * w; accB[t] += b * w;
            }
        }
    }
    u32* oh = (u32*)(outh + (size_t)wv * DIMS);
    u32* ol = OUTS ? (u32*)(outl + (size_t)wv * DIMS) : nullptr;
#pragma unroll
    for (int t = 0; t < NT; ++t) {
        int p = lane + 64 * t;
        if (p < NP) {
            if (OUTS == 0) {
                oh[p] = pack2(accA[t], accB[t]);
            } else {
                u16 ha = f2bf(accA[t]), hb_ = f2bf(accB[t]);
                u16 la = f2bf(accA[t] - bf2f(ha)), lb = f2bf(accB[t] - bf2f(hb_));
                oh[p] = (u32)ha | ((u32)hb_ << 16);
                ol[p] = (u32)la | ((u32)lb << 16);
            }
        }
    }
}

// ---------------- fused segment mean + pooled (4-way unrolled) ----------------
__global__ void k_segpool(const int* __restrict__ rpX, const int* __restrict__ mids,
                          const u16* __restrict__ e_buf, u16* __restrict__ pooled, int n) {
    int nv = (blockIdx.x * blockDim.x + threadIdx.x) >> 6;
    if (nv >= n) return;
    int lane = threadIdx.x & 63;
    int beg = rpX[nv], end = rpX[nv + 1];
    int cnt = end - beg;
    float accA[2] = {0.f, 0.f}, accB[2] = {0.f, 0.f};
    int e = beg;
    for (; e + 4 <= end; e += 4) {
        const u32* r0 = (const u32*)(e_buf + (size_t)mids[e] * DD);
        const u32* r1 = (const u32*)(e_buf + (size_t)mids[e + 1] * DD);
        const u32* r2 = (const u32*)(e_buf + (size_t)mids[e + 2] * DD);
        const u32* r3 = (const u32*)(e_buf + (size_t)mids[e + 3] * DD);
        u32 v[4][2];
#pragma unroll
        for (int t = 0; t < 2; ++t) {
            int p = lane + 64 * t;
            if (p < DD / 2) { v[0][t] = r0[p]; v[1][t] = r1[p]; v[2][t] = r2[p]; v[3][t] = r3[p]; }
        }
#pragma unroll
        for (int t = 0; t < 2; ++t) {
            int p = lane + 64 * t;
            if (p < DD / 2) {
                float a, b;
                unpack2(v[0][t], a, b); accA[t] += a; accB[t] += b;
                unpack2(v[1][t], a, b); accA[t] += a; accB[t] += b;
                unpack2(v[2][t], a, b); accA[t] += a; accB[t] += b;
                unpack2(v[3][t], a, b); accA[t] += a; accB[t] += b;
            }
        }
    }
    for (; e < end; ++e) {
        const u32* r = (const u32*)(e_buf + (size_t)mids[e] * DD);
#pragma unroll
        for (int t = 0; t < 2; ++t) {
            int p = lane + 64 * t;
            if (p < DD / 2) { float a, b; unpack2(r[p], a, b); accA[t] += a; accB[t] += b; }
        }
    }
    float inv = 1.0f / fmaxf((float)cnt, 1.0f);
    bool occ = cnt > 0;
    const u32* er = (const u32*)(e_buf + (size_t)nv * DD);
    u32* p0 = (u32*)(pooled + (size_t)nv * (2 * DD));
#pragma unroll
    for (int t = 0; t < 2; ++t) {
        int p = lane + 64 * t;
        if (p < DD / 2) {
            p0[p] = occ ? er[p] : 0u;
            p0[DD / 2 + p] = occ ? pack2(accA[t] * inv, accB[t] * inv) : 0u;
        }
    }
}

// ---------------- MFMA matmul, software-pipelined K-loop ----------------
template<int AMODE, int BLO, int RELU_IN, int RELU_OUT, int HAS_BIAS, int HAS_ADD, int FUSE, int CMODE>
__global__ __launch_bounds__(256) void k_mfmamm(
    const u16* __restrict__ Ah, const u16* __restrict__ Al,
    const u16* __restrict__ Bh, const u16* __restrict__ Bl,
    void* __restrict__ Cv, u16* __restrict__ Cl,
    int Mr, int Nc, int Kd, int redrows,
    const float* __restrict__ bias, const u16* __restrict__ addsrc,
    const int* __restrict__ addidx, const float* __restrict__ tvec,
    float* __restrict__ redout) {
    constexpr int BM = 128, BK = 32;
    constexpr int ASTR = 40;
    __shared__ u16 Ahs[2][BM * ASTR];
    __shared__ u16 Als[AMODE ? 2 : 1][AMODE ? (BM * ASTR) : 8];

    int tid = threadIdx.x;
    int wid = tid >> 6, lane = tid & 63;
    int wr = wid >> 1, wc = wid & 1;
    int r = lane & 15, h = lane >> 4;
    int bm0 = blockIdx.y * BM, bn0 = blockIdx.x * 128;
    int srow = (tid & 15) + 16 * (tid >> 6);
    int sg = (tid >> 4) & 3;
    int nk = (Kd + BK - 1) / BK;

    f32x4 acc[4][4];
#pragma unroll
    for (int i = 0; i < 4; ++i)
#pragma unroll
        for (int j = 0; j < 4; ++j) acc[i][j] = (f32x4){0.f, 0.f, 0.f, 0.f};

    uint4 pa[2], pl[2];
    {
        int kc = sg * 8;
        bool kok = (kc + 8 <= Kd);
#pragma unroll
        for (int it = 0; it < 2; ++it) {
            int row = srow + 64 * it;
            int gr = bm0 + row;
            uint4 v = make_uint4(0, 0, 0, 0), vl2 = make_uint4(0, 0, 0, 0);
            if (gr < Mr && kok) {
                v = *(const uint4*)(Ah + (size_t)gr * Kd + kc);
                if (AMODE) vl2 = *(const uint4*)(Al + (size_t)gr * Kd + kc);
            }
            if (RELU_IN) {
                v.x = relu2bf(v.x); v.y = relu2bf(v.y);
                v.z = relu2bf(v.z); v.w = relu2bf(v.w);
            }
            pa[it] = v;
            if (AMODE) pl[it] = vl2;
        }
#pragma unroll
        for (int it = 0; it < 2; ++it) {
            int row = srow + 64 * it;
            *(uint4*)(&Ahs[0][row * ASTR + sg * 8]) = pa[it];
            if (AMODE) *(uint4*)(&Als[0][row * ASTR + sg * 8]) = pl[it];
        }
    }
    __syncthreads();

    for (int k = 0; k < nk; ++k) {
        int cur = k & 1;
        uint4 na[2], nl[2];
        bool have_next = (k + 1 < nk);
        if (have_next) {
            int kc = (k + 1) * BK + sg * 8;
            bool kok = (kc + 8 <= Kd);
#pragma unroll
            for (int it = 0; it < 2; ++it) {
                int row = srow + 64 * it;
                int gr = bm0 + row;
                uint4 v = make_uint4(0, 0, 0, 0), vl2 = make_uint4(0, 0, 0, 0);
                if (gr < Mr && kok) {
                    v = *(const uint4*)(Ah + (size_t)gr * Kd + kc);
                    if (AMODE) vl2 = *(const uint4*)(Al + (size_t)gr * Kd + kc);
                }
                if (RELU_IN) {
                    v.x = relu2bf(v.x); v.y = relu2bf(v.y);
                    v.z = relu2bf(v.z); v.w = relu2bf(v.w);
                }
                na[it] = v;
                if (AMODE) nl[it] = vl2;
            }
        }
        bf16x8 bh4[4], bl4[4];
        {
            int kb = k * BK + h * 8;
            bool kbok = (kb + 8 <= Kd);
#pragma unroll
            for (int j = 0; j < 4; ++j) {
                int nrow = bn0 + wc * 64 + j * 16 + r;
                if (nrow < Nc && kbok) {
                    bh4[j] = *(const bf16x8*)(Bh + (size_t)nrow * Kd + kb);
                    if (BLO) bl4[j] = *(const bf16x8*)(Bl + (size_t)nrow * Kd + kb);
                } else { bh4[j] = zero8(); if (BLO) bl4[j] = zero8(); }
            }
        }
        bf16x8 af[4], alr[4];
#pragma unroll
        for (int i = 0; i < 4; ++i) {
            int mrow = wr * 64 + i * 16 + r;
            af[i] = *(const bf16x8*)(&Ahs[cur][mrow * ASTR + h * 8]);
            if (AMODE) alr[i] = *(const bf16x8*)(&Als[cur][mrow * ASTR + h * 8]);
        }
#pragma unroll
        for (int i = 0; i < 4; ++i)
#pragma unroll
            for (int j = 0; j < 4; ++j) {
                acc[i][j] = __builtin_amdgcn_mfma_f32_16x16x32_bf16(af[i], bh4[j], acc[i][j], 0, 0, 0);
                if (BLO)
                    acc[i][j] = __builtin_amdgcn_mfma_f32_16x16x32_bf16(af[i], bl4[j], acc[i][j], 0, 0, 0);
                if (AMODE)
                    acc[i][j] = __builtin_amdgcn_mfma_f32_16x16x32_bf16(alr[i], bh4[j], acc[i][j], 0, 0, 0);
            }
        if (have_next) {
#pragma unroll
            for (int it = 0; it < 2; ++it) {
                int row = srow + 64 * it;
                *(uint4*)(&Ahs[cur ^ 1][row * ASTR + sg * 8]) = na[it];
                if (AMODE) *(uint4*)(&Als[cur ^ 1][row * ASTR + sg * 8]) = nl[it];
            }
        }
        __syncthreads();
    }
    // ---- epilogue ----
    float colacc[4] = {0.f, 0.f, 0.f, 0.f};
#pragma unroll
    for (int i = 0; i < 4; ++i) {
        float rowacc[4] = {0.f, 0.f, 0.f, 0.f};
#pragma unroll
        for (int j = 0; j < 4; ++j) {
            int col = bn0 + wc * 64 + j * 16 + r;
            bool colok = col < Nc;
            float tv = (FUSE == 2 && colok) ? tvec[col] : 0.f;
#pragma unroll
            for (int rg = 0; rg < 4; ++rg) {
                int row = bm0 + wr * 64 + i * 16 + h * 4 + rg;
                float v = acc[i][j][rg];
                if (HAS_BIAS && colok) v += bias[col];
                if (RELU_OUT) v = fmaxf(v, 0.f);
                bool ok = colok && row < Mr;
                if (HAS_ADD && ok) {
                    int r2 = addidx ? addidx[row] : row;
                    v += bf2f(addsrc[(size_t)r2 * Nc + col]);
                }
                if (FUSE != 2 && ok) {
                    size_t cidx = (size_t)row * Nc + col;
                    if (CMODE == 0) ((u16*)Cv)[cidx] = f2bf(v);
                    else if (CMODE == 1) ((float*)Cv)[cidx] = v;
                    else {
                        u16 hi_ = f2bf(v);
                        ((u16*)Cv)[cidx] = hi_;
                        Cl[cidx] = f2bf(v - bf2f(hi_));
                    }
                }
                if (FUSE == 1 && ok && row < redrows) colacc[j] += v;
                if (FUSE == 2) rowacc[rg] += v * tv;
            }
        }
        if (FUSE == 2) {
#pragma unroll
            for (int rg = 0; rg < 4; ++rg) {
                float val = rowacc[rg];
                val += __shfl_xor(val, 1); val += __shfl_xor(val, 2);
                val += __shfl_xor(val, 4); val += __shfl_xor(val, 8);
                int row = bm0 + wr * 64 + i * 16 + h * 4 + rg;
                if (r == 0 && row < Mr) atomicAdd(&redout[row], val);
            }
        }
    }
    if (FUSE == 1) {
#pragma unroll
        for (int j = 0; j < 4; ++j) {
            float val = colacc[j];
            val += __shfl_xor(val, 16); val += __shfl_xor(val, 32);
            int col = bn0 + wc * 64 + j * 16 + r;
            if (h == 0 && col < Nc) atomicAdd(&redout[col], val);
        }
    }
}

// ---------------- DGI helpers ----------------
__global__ void k_tmv(const float* __restrict__ Wd, const float* __restrict__ csum,
                      float* __restrict__ tvec) {
    __shared__ float c[HIDD];
    int lane = threadIdx.x;
    for (int j = lane; j < HIDD; j += 64)
        c[j] = 1.0f / (1.0f + expf(-csum[j] * (1.0f / (float)NN)));
    __syncthreads();
    int r0 = blockIdx.x * 16;
    for (int i = r0; i < r0 + 16; ++i) {
        const float* wr = Wd + (size_t)i * HIDD;
        float s = 0.f;
        for (int j = lane; j < HIDD; j += 64) s += wr[j] * c[j];
        s = wredsum(s);
        if (lane == 0) tvec[i] = s;
    }
}

__global__ void k_rowdot512(const float* __restrict__ p, const float* __restrict__ t,
                            float* __restrict__ out, int rows) {
    int g = blockIdx.x * blockDim.x + threadIdx.x;
    int wv = g >> 6;
    if (wv >= rows) return;
    int lane = g & 63;
    const float* r = p + (size_t)wv * HIDD;
    float s = 0.f;
#pragma unroll
    for (int t4 = 0; t4 < 8; ++t4) {
        int d = lane + t4 * 64;
        s += r[d] * t[d];
    }
    s = wredsum(s);
    if (lane == 0) out[wv] = s;
}

__global__ void k_rowdot512b(const u16* __restrict__ p, const float* __restrict__ t,
                             float* __restrict__ out, int rows) {
    int g = blockIdx.x * blockDim.x + threadIdx.x;
    int wv = g >> 6;
    if (wv >= rows) return;
    int lane = g & 63;
    const u32* r = (const u32*)(p + (size_t)wv * HIDD);
    float s = 0.f;
#pragma unroll
    for (int t4 = 0; t4 < 4; ++t4) {
        int pp = lane + t4 * 64;
        float a, b;
        unpack2(r[pp], a, b);
        s += a * t[2 * pp] + b * t[2 * pp + 1];
    }
    s = wredsum(s);
    if (lane == 0) out[wv] = s;
}

// ---------------- ConvKB ----------------
__global__ void k_convkb(const u16* __restrict__ ec, const float* __restrict__ rel,
                         const int* __restrict__ bi, const float* __restrict__ cw,
                         const float* __restrict__ cb, const float* __restrict__ fcw,
                         const float* __restrict__ fcb, float* __restrict__ out) {
    __shared__ float t0[DD], t1[DD], t2[DD];
    __shared__ float red[4];
    int b = blockIdx.x, tid = threadIdx.x;
    int i0 = bi[b * 3 + 0], i1 = bi[b * 3 + 1], i2 = bi[b * 3 + 2];
    if (tid < DD) {
        t0[tid] = bf2f(ec[(size_t)i0 * DD + tid]);
        t1[tid] = rel[(size_t)i1 * DD + tid];
        t2[tid] = bf2f(ec[(size_t)i2 * DD + tid]);
    }
    __syncthreads();
    float partial = 0.f;
    if (tid < DD) {
        float a = t0[tid], bb = t1[tid], c = t2[tid];
        for (int o = 0; o < OCC; ++o) {
            float h = fmaxf(cw[o * 3 + 0] * a + cw[o * 3 + 1] * bb + cw[o * 3 + 2] * c + cb[o], 0.f);
            partial += h * fcw[o * DD + tid];
        }
    }
    partial = wredsum(partial);
    if ((tid & 63) == 0) red[tid >> 6] = partial;
    __syncthreads();
    if (tid == 0) out[b] = red[0] + red[1] + red[2] + red[3] + fcb[0];
}

__global__ void k_sentinel(float* out, float val) { out[threadIdx.x] = val; }

extern "C" void kernel_launch(void* const* d_in, const int* in_sizes, int n_in,
                              void* d_out, int out_size, void* d_ws, size_t ws_size,
                              hipStream_t stream) {
    const float* entity_emb = (const float*)d_in[0];
    const float* rel_emb    = (const float*)d_in[1];
    const int*   b_x        = (const int*)d_in[2];
    const int*   b_gi       = (const int*)d_in[3];
    const int*   e_src      = (const int*)d_in[4];
    const int*   e_dst      = (const int*)d_in[5];
    const float* e_w        = (const float*)d_in[6];
    const int*   big_src    = (const int*)d_in[7];
    const int*   big_dst    = (const int*)d_in[8];
    const float* big_w      = (const float*)d_in[9];
    const int*   perm       = (const int*)d_in[10];
    const int*   batch_in   = (const int*)d_in[11];
    const float* W1a        = (const float*)d_in[12];
    const float* W1b        = (const float*)d_in[13];
    const float* W2a        = (const float*)d_in[14];
    const float* W2b        = (const float*)d_in[15];
    // Wle/ble unused: segment softmax weights sum to exactly 1 and every row in a
    // segment shares the same emb vector -> pooled[n] == occ(n)*concat(e[n],mean[n])
    const float* Wlo        = (const float*)d_in[18];
    const float* blo        = (const float*)d_in[19];
    const float* Wg         = (const float*)d_in[20];
    const float* Wd         = (const float*)d_in[21];
    const float* conv_w     = (const float*)d_in[22];
    const float* conv_b     = (const float*)d_in[23];
    const float* fc_w       = (const float*)d_in[24];
    const float* fc_b       = (const float*)d_in[25];
    float* out = (float*)d_out;

    size_t off = 0;
    auto balloc = [&](size_t nbytes) {
        size_t p = off;
        off += (nbytes + 511) & ~(size_t)511;
        return p;
    };
    char* base = (char*)d_ws;
    u16*   entb = (u16*)(base + balloc((size_t)NN * DD * 2));
    float* relf = (float*)(base + balloc((size_t)RR * DD * 4));
    u16*   relb = (u16*)(base + balloc((size_t)RR * DD * 2));
    u16*   Pent = (u16*)(base + balloc((size_t)NN * HH1 * 2));
    u16*   Prel = (u16*)(base + balloc((size_t)RR * HH1 * 2));
    int*   idx1 = (int*)(base + balloc((size_t)MM * 4));
    int*   rpB  = (int*)(base + balloc((size_t)(NN + 1) * 4));
    int*   srcB = (int*)(base + balloc((size_t)NEE * 4));
    float* wB   = (float*)(base + balloc((size_t)NEE * 4));
    int*   rpE  = (int*)(base + balloc((size_t)(MM + 1) * 4));
    int*   srcE = (int*)(base + balloc((size_t)EE * 4));
    float* wE   = (float*)(base + balloc((size_t)EE * 4));
    int*   ivE  = (int*)(base + balloc((size_t)EE * 4));
    int*   giE  = (int*)(base + balloc((size_t)EE * 4));
    int*   rpX  = (int*)(base + balloc((size_t)(NN + 1) * 4));
    int*   mids = (int*)(base + balloc((size_t)MM * 4));
    int*   curB = (int*)(base + balloc((size_t)NN * 4));
    int*   curE = (int*)(base + balloc((size_t)MM * 4));
    int*   curX = (int*)(base + balloc((size_t)NN * 4));
    u16* w1aT_h  = (u16*)(base + balloc(200 * 256 * 2));
    u16* w1aT_l  = (u16*)(base + balloc(200 * 256 * 2));
    u16* w1abT_h = (u16*)(base + balloc(200 * 256 * 2));
    u16* w1abT_l = (u16*)(base + balloc(200 * 256 * 2));
    u16* w1bT_h  = (u16*)(base + balloc(256 * 200 * 2));
    u16* w1bT_l  = (u16*)(base + balloc(256 * 200 * 2));
    u16* wloT_h  = (u16*)(base + balloc(400 * 200 * 2));
    u16* wloT_l  = (u16*)(base + balloc(400 * 200 * 2));
    u16* wgT_h   = (u16*)(base + balloc(200 * 512 * 2));
    u16* wgT_l   = (u16*)(base + balloc(200 * 512 * 2));
    u16* w2aT_h  = (u16*)(base + balloc(200 * 256 * 2));
    u16* w2aT_l  = (u16*)(base + balloc(200 * 256 * 2));
    u16* w2bgT_h = (u16*)(base + balloc(512 * 256 * 2));
    u16* w2bgT_l = (u16*)(base + balloc(512 * 256 * 2));
    char*  Aarena = base + balloc((size_t)MM * HH1 * 2);   // 61.44 MB
    char*  Barena = base + balloc((size_t)MM * DD * 2);    // 48 MB
    char*  Carena = base + balloc((size_t)MM * DD * 2);    // 48 MB
    float* csum = (float*)(base + balloc(4 * 2048));
    float* cvec = csum + 512;
    float* t_l  = csum + 1024;
    float* t_g  = csum + 1536;
    // ecb LAST so an optional second plane can sit contiguously after it
    u16*   ecb  = (u16*)(base + balloc((size_t)NN * DD * 2));
    size_t off_small = off;
    u16*   ecb2 = ecb + (size_t)NN * DD;
    bool bigws = (off_small + (size_t)NN * DD * 2) <= ws_size;
    (void)cvec;

    if (ws_size < off_small) {
        k_sentinel<<<dim3(1), dim3(8), 0, stream>>>(out, (float)(ws_size >> 20));
        return;
    }

    const size_t PL = 20000000;   // 20 MB plane (NN*DD*2)
    const size_t PH = 25600000;   // 25.6 MB plane (NN*HH1*2)
    u16*   aggx   = (u16*)Aarena;                  // [MM,256] bf16
    u16*   hb     = (u16*)Barena;                  // [MM,200] bf16
    u16*   e_buf  = (u16*)Carena;                  // [MM,200] bf16
    u16*   pooled = (u16*)Aarena;                  // [NN,400] bf16
    u16*   a1h    = (u16*)Aarena;                  // [NN,200] split pair
    u16*   a1l    = (u16*)(Aarena + PL);
    u16*   h2h    = (u16*)Barena;                  // [NN,256] split pair (spans B..C)
    u16*   h2l    = (u16*)(Barena + PH);
    u16*   g2h    = (u16*)Aarena;                  // [NN,256] split pair (a1 dead)
    u16*   g2l    = (u16*)(Aarena + PH);
    u16*   pb16   = (u16*)Barena;                  // [NN,512] bf16 (global DGI v0)
    u16*   pb16L  = (u16*)Aarena;                  // [2NN,512] bf16 (merged local DGI, A..B)
    float* pbuf   = (float*)Aarena;                // [NN,512] f32 (small-path local DGI)

    dim3 blk(256);
    auto wgrid = [](int items) { return dim3((unsigned)((items + 3) / 4)); };
    auto tgrid = [](int items) { return dim3((unsigned)((items + 255) / 256)); };
    auto mmgrid = [](int Mr, int Nc) { return dim3((unsigned)((Nc + 127) / 128), (unsigned)((Mr + 127) / 128)); };

    // ---- normalize (merged) + perm gather + weight prep ----
    k_l2norm2<<<wgrid(NN + RR), blk, 0, stream>>>(entity_emb, rel_emb, entb, relf, relb);
    k_gather_perm<<<tgrid(MM), blk, 0, stream>>>(b_x, perm, idx1, MM);
    k_prepw<<<tgrid(256 * 200), blk, 0, stream>>>(W1a, 256, 200, w1aT_h, w1aT_l);
    k_prepw<<<tgrid(256 * 200), blk, 0, stream>>>(W1a + 200 * 256, 256, 200, w1abT_h, w1abT_l);
    k_prepw<<<tgrid(200 * 256), blk, 0, stream>>>(W1b, 200, 256, w1bT_h, w1bT_l);
    k_prepw<<<tgrid(200 * 400), blk, 0, stream>>>(Wlo, 200, 400, wloT_h, wloT_l);
    k_prepw<<<tgrid(512 * 200), blk, 0, stream>>>(Wg, 512, 200, wgT_h, wgT_l);
    k_prepw<<<tgrid(256 * 200), blk, 0, stream>>>(W2a, 256, 200, w2aT_h, w2aT_l);
    k_fusew<<<tgrid(512 * 256), blk, 0, stream>>>(W2b, Wg, w2bgT_h, w2bgT_l);

    // ---- CSR builds (merged hist, scan writes cursors) ----
    hipMemsetAsync(curB, 0, (size_t)NN * 4, stream);
    hipMemsetAsync(curE, 0, (size_t)MM * 4, stream);
    hipMemsetAsync(curX, 0, (size_t)NN * 4, stream);
    k_hist3<<<tgrid(NEE + EE + MM), blk, 0, stream>>>(big_dst, curB, NEE,
                                                      e_dst, curE, EE, b_x, curX, MM);
    k_scan3<<<dim3(3), dim3(1024), 0, stream>>>(curB, rpB, curB, NN,
                                                curE, rpE, curE, MM,
                                                curX, rpX, curX, NN);
    k_fill2<<<tgrid(NEE), blk, 0, stream>>>(big_dst, big_src, big_w, curB, srcB, wB, NEE);
    k_fill2<<<tgrid(EE), blk, 0, stream>>>(e_dst, e_src, e_w, curE, srcE, wE, EE);
    k_fill1<<<tgrid(MM), blk, 0, stream>>>(b_x, curX, mids, MM);
    k_edge_idx<<<tgrid(EE), blk, 0, stream>>>(srcE, b_gi, giE, EE);

    // ---- P_ent / P_rel ----
    k_mfmamm<0, 0, 0, 0, 0, 0, 0, 0><<<mmgrid(NN, HH1), blk, 0, stream>>>(
        entb, nullptr, w1aT_h, w1aT_l, Pent, nullptr, NN, HH1, DD, NN,
        nullptr, nullptr, nullptr, nullptr, nullptr);
    k_mfmamm<0, 0, 0, 0, 0, 0, 0, 0><<<mmgrid(RR, HH1), blk, 0, stream>>>(
        relb, nullptr, w1abT_h, w1abT_l, Prel, nullptr, RR, HH1, DD, RR,
        nullptr, nullptr, nullptr, nullptr, nullptr);

    auto mce_pass = [&](int v, u16* ecdst) {
        const int* ivmap  = v ? idx1 : b_x;
        const int* addidx = v ? perm : nullptr;
        k_edge_idx<<<tgrid(EE), blk, 0, stream>>>(srcE, ivmap, ivE, EE);
        k_pull_mce<<<wgrid(MM), blk, 0, stream>>>(rpE, ivE, giE, wE, Pent, Prel, aggx, MM);
        k_mfmamm<0, 0, 1, 0, 0, 0, 0, 0><<<mmgrid(MM, DD), blk, 0, stream>>>(
            aggx, nullptr, w1bT_h, w1bT_l, hb, nullptr, MM, DD, HH1, MM,
            nullptr, nullptr, nullptr, nullptr, nullptr);
        k_pull<DD, 0, 0><<<wgrid(MM), blk, 0, stream>>>(rpE, srcE, wE, hb, nullptr,
                                                        e_buf, nullptr, MM);
        k_segpool<<<wgrid(NN), blk, 0, stream>>>(rpX, mids, e_buf, pooled, NN);
        k_mfmamm<0, 0, 0, 0, 1, 1, 0, 0><<<mmgrid(NN, DD), blk, 0, stream>>>(
            pooled, nullptr, wloT_h, wloT_l, ecdst, nullptr, NN, DD, 2 * DD, NN,
            blo, entb, addidx, nullptr, nullptr);
    };

    auto gcn_pass = [&](int v, const u16* ecsrc) {
        k_pull<DD, 0, 1><<<wgrid(NN), blk, 0, stream>>>(rpB, srcB, wB, ecsrc, nullptr,
                                                        a1h, a1l, NN);
        k_mfmamm<1, 1, 0, 1, 0, 0, 0, 2><<<mmgrid(NN, HH1), blk, 0, stream>>>(
            a1h, a1l, w2aT_h, w2aT_l, h2h, h2l, NN, HH1, DD, NN,
            nullptr, nullptr, nullptr, nullptr, nullptr);
        k_pull<HH1, 1, 1><<<wgrid(NN), blk, 0, stream>>>(rpB, srcB, wB, h2h, h2l,
                                                         g2h, g2l, NN);
        if (v == 0) {
            hipMemsetAsync(csum, 0, 512 * sizeof(float), stream);
            k_mfmamm<1, 1, 0, 1, 0, 0, 1, 0><<<mmgrid(NN, HIDD), blk, 0, stream>>>(
                g2h, g2l, w2bgT_h, w2bgT_l, pb16, nullptr, NN, HIDD, HH1, NN,
                nullptr, nullptr, nullptr, nullptr, csum);
            k_tmv<<<dim3(32), dim3(64), 0, stream>>>(Wd, csum, t_g);
            k_rowdot512b<<<wgrid(NN), blk, 0, stream>>>(pb16, t_g, out + BB + 2 * (size_t)NN, NN);
        } else {
            hipMemsetAsync(out + BB + 3 * (size_t)NN, 0, (size_t)NN * 4, stream);
            k_mfmamm<1, 1, 0, 1, 0, 0, 2, 0><<<mmgrid(NN, HIDD), blk, 0, stream>>>(
                g2h, g2l, w2bgT_h, w2bgT_l, nullptr, nullptr, NN, HIDD, HH1, NN,
                nullptr, nullptr, nullptr, t_g, out + BB + 3 * (size_t)NN);
        }
    };

    if (bigws) {
        mce_pass(0, ecb);
        mce_pass(1, ecb2);
        hipMemsetAsync(csum, 0, 512 * sizeof(float), stream);
        k_mfmamm<0, 0, 0, 1, 0, 0, 1, 0><<<mmgrid(2 * NN, HIDD), blk, 0, stream>>>(
            ecb, nullptr, wgT_h, wgT_l, pb16L, nullptr, 2 * NN, HIDD, DD, NN,
            nullptr, nullptr, nullptr, nullptr, csum);
        k_tmv<<<dim3(32), dim3(64), 0, stream>>>(Wd, csum, t_l);
        k_rowdot512b<<<wgrid(2 * NN), blk, 0, stream>>>(pb16L, t_l, out + BB, 2 * NN);
        k_convkb<<<dim3(BB), blk, 0, stream>>>(ecb, relf, batch_in,
                                               conv_w, conv_b, fc_w, fc_b, out);
        gcn_pass(0, ecb);
        gcn_pass(1, ecb2);
    } else {
        for (int v = 0; v < 2; ++v) {
            mce_pass(v, ecb);
            if (v == 0) {
                hipMemsetAsync(csum, 0, 512 * sizeof(float), stream);
                k_mfmamm<0, 0, 0, 1, 0, 0, 1, 1><<<mmgrid(NN, HIDD), blk, 0, stream>>>(
                    ecb, nullptr, wgT_h, wgT_l, pbuf, nullptr, NN, HIDD, DD, NN,
                    nullptr, nullptr, nullptr, nullptr, csum);
                k_tmv<<<dim3(32), dim3(64), 0, stream>>>(Wd, csum, t_l);
                k_rowdot512<<<wgrid(NN), blk, 0, stream>>>(pbuf, t_l, out + BB, NN);
                k_convkb<<<dim3(BB), blk, 0, stream>>>(ecb, relf, batch_in,
                                                       conv_w, conv_b, fc_w, fc_b, out);
            } else {
                hipMemsetAsync(out + BB + NN, 0, (size_t)NN * 4, stream);
                k_mfmamm<0, 0, 0, 1, 0, 0, 2, 1><<<mmgrid(NN, HIDD), blk, 0, stream>>>(
                    ecb, nullptr, wgT_h, wgT_l, nullptr, nullptr, NN, HIDD, DD, NN,
                    nullptr, nullptr, nullptr, t_l, out + BB + NN);
            }
            gcn_pass(v, ecb);
        }
    }

    (void)in_sizes; (void)n_in; (void)out_size;
}

// Round 17
// 1883.425 us; speedup vs baseline: 1.0943x; 1.0943x over previous
//
#include <hip/hip_runtime.h>

#define NN   50000
#define RR   500
#define MM   120000
#define EE   960000
#define NEE  800000
#define BB   8192
#define DD   200
#define HH1  256
#define HIDD 512
#define OCC  50

typedef unsigned int  u32;
typedef unsigned short u16;
typedef __attribute__((ext_vector_type(8))) short bf16x8;
typedef __attribute__((ext_vector_type(4))) float f32x4;

static __device__ __forceinline__ float bf2f(u16 u) {
    u32 x = ((u32)u) << 16;
    return __uint_as_float(x);
}
static __device__ __forceinline__ u16 f2bf(float f) {
    u32 x = __float_as_uint(f);
    u32 r = (x + 0x7FFFu + ((x >> 16) & 1u)) >> 16;
    return (u16)r;
}
static __device__ __forceinline__ u32 pack2(float a, float b) {
    return (u32)f2bf(a) | ((u32)f2bf(b) << 16);
}
static __device__ __forceinline__ void unpack2(u32 v, float& a, float& b) {
    a = bf2f((u16)(v & 0xFFFFu));
    b = bf2f((u16)(v >> 16));
}

static __device__ __forceinline__ float wredsum(float v) {
#pragma unroll
    for (int off = 32; off > 0; off >>= 1) v += __shfl_xor(v, off);
    return v;
}

static __device__ __forceinline__ u32 relu2bf(u32 x) {
    if (x & 0x00008000u) x &= 0xFFFF0000u;
    if (x & 0x80000000u) x &= 0x0000FFFFu;
    return x;
}
static __device__ __forceinline__ bf16x8 zero8() {
    bf16x8 z;
#pragma unroll
    for (int i = 0; i < 8; ++i) z[i] = 0;
    return z;
}

// ---------------- merged l2 normalize ----------------
__global__ void k_l2norm2(const float* __restrict__ ent_in, const float* __restrict__ rel_in,
                          u16* __restrict__ entb, float* __restrict__ relf,
                          u16* __restrict__ relb) {
    int w = (blockIdx.x * blockDim.x + threadIdx.x) >> 6;
    int lane = threadIdx.x & 63;
    if (w >= NN + RR) return;
    bool isent = w < NN;
    const float* r = isent ? (ent_in + (size_t)w * DD) : (rel_in + (size_t)(w - NN) * DD);
    float s = 0.f;
    for (int d = lane; d < DD; d += 64) { float v = r[d]; s += v * v; }
    s = wredsum(s);
    float inv = 1.0f / fmaxf(sqrtf(s), 1e-12f);
    for (int d = lane; d < DD; d += 64) {
        float v = r[d] * inv;
        if (isent) {
            entb[(size_t)w * DD + d] = f2bf(v);
        } else {
            relf[(size_t)(w - NN) * DD + d] = v;
            relb[(size_t)(w - NN) * DD + d] = f2bf(v);
        }
    }
}

__global__ void k_gather_perm(const int* __restrict__ bx, const int* __restrict__ perm,
                              int* __restrict__ idx1, int M) {
    int m = blockIdx.x * blockDim.x + threadIdx.x;
    if (m < M) idx1[m] = perm[bx[m]];
}

__global__ void k_edge_idx(const int* __restrict__ srcE, const int* __restrict__ map,
                           int* __restrict__ outE, int n) {
    int e = blockIdx.x * blockDim.x + threadIdx.x;
    if (e < n) outE[e] = map[srcE[e]];
}

// weight prep: split f32 [Kd][Nc] into transposed bf16 hi/lo planes [Nc][Kd]
__global__ void k_prepw(const float* __restrict__ src, int Nc, int Kd,
                        u16* __restrict__ hi, u16* __restrict__ lo) {
    int i = blockIdx.x * blockDim.x + threadIdx.x;
    if (i >= Nc * Kd) return;
    int n = i / Kd, k = i - n * Kd;
    float b = src[(size_t)k * Nc + n];
    u16 hb_ = f2bf(b);
    hi[i] = hb_;
    lo[i] = f2bf(b - bf2f(hb_));
}

// fused weight: W2bg = W2b[256,200] @ Wg[200,512] -> planes [512][256]
__global__ void k_fusew(const float* __restrict__ W2b, const float* __restrict__ Wg,
                        u16* __restrict__ hi, u16* __restrict__ lo) {
    int i = blockIdx.x * blockDim.x + threadIdx.x;
    if (i >= HIDD * HH1) return;
    int n = i >> 8, k = i & 255;
    float s = 0.f;
    for (int j = 0; j < DD; ++j) s += W2b[k * DD + j] * Wg[(size_t)j * HIDD + n];
    u16 h = f2bf(s);
    hi[i] = h;
    lo[i] = f2bf(s - bf2f(h));
}

// ---------------- CSR build ----------------
__global__ void k_hist3(const int* __restrict__ i0, int* __restrict__ c0, int n0,
                        const int* __restrict__ i1, int* __restrict__ c1, int n1,
                        const int* __restrict__ i2, int* __restrict__ c2, int n2) {
    int i = blockIdx.x * blockDim.x + threadIdx.x;
    if (i < n0) { atomicAdd(&c0[i0[i]], 1); return; }
    i -= n0;
    if (i < n1) { atomicAdd(&c1[i1[i]], 1); return; }
    i -= n1;
    if (i < n2) atomicAdd(&c2[i2[i]], 1);
}

// ---- multi-block 3-phase exclusive scan over three arrays ----
// phase A: per-4096-chunk block scan; writes in-chunk exclusive prefix + chunk total
__global__ __launch_bounds__(1024) void k_scanA(
    const int* __restrict__ inB, int* __restrict__ outB, int nB_,
    const int* __restrict__ inE, int* __restrict__ outE, int nE_,
    const int* __restrict__ inX, int* __restrict__ outX, int nX_,
    int* __restrict__ bsum) {
    int arr = blockIdx.y;
    const int* in = (arr == 0) ? inB : (arr == 1) ? inE : inX;
    int* out = (arr == 0) ? outB : (arr == 1) ? outE : outX;
    int n = (arr == 0) ? nB_ : (arr == 1) ? nE_ : nX_;
    int chunk = blockIdx.x;
    if (chunk * 4096 >= n) return;
    __shared__ int wtot[16];
    __shared__ int wexc[16];
    int tid = threadIdx.x, lane = tid & 63, wid = tid >> 6;
    int base = chunk * 4096 + tid * 4;
    int v0 = (base + 0 < n) ? in[base + 0] : 0;
    int v1 = (base + 1 < n) ? in[base + 1] : 0;
    int v2 = (base + 2 < n) ? in[base + 2] : 0;
    int v3 = (base + 3 < n) ? in[base + 3] : 0;
    int tsum = v0 + v1 + v2 + v3;
    int x = tsum;
#pragma unroll
    for (int off = 1; off < 64; off <<= 1) {
        int t = __shfl_up(x, off);
        if (lane >= off) x += t;
    }
    if (lane == 63) wtot[wid] = x;
    __syncthreads();
    if (wid == 0) {
        int wv = (lane < 16) ? wtot[lane] : 0;
        int y = wv;
#pragma unroll
        for (int off = 1; off < 16; off <<= 1) {
            int t = __shfl_up(y, off);
            if (lane >= off) y += t;
        }
        if (lane < 16) wexc[lane] = y - wv;
        if (lane == 15) bsum[arr * 64 + chunk] = y;   // chunk total
    }
    __syncthreads();
    int texcl = (x - tsum) + wexc[wid];
    if (base + 0 < n) out[base + 0] = texcl;
    if (base + 1 < n) out[base + 1] = texcl + v0;
    if (base + 2 < n) out[base + 2] = texcl + v0 + v1;
    if (base + 3 < n) out[base + 3] = texcl + v0 + v1 + v2;
}

// phase B: tiny serial scan of chunk totals per array (3 lanes)
__global__ void k_scanB(int* __restrict__ bsum, int* __restrict__ boff,
                        int* __restrict__ tot, int nB_, int nE_, int nX_) {
    int arr = threadIdx.x;
    if (arr >= 3) return;
    int n = (arr == 0) ? nB_ : (arr == 1) ? nE_ : nX_;
    int nc = (n + 4095) / 4096;
    int acc = 0;
    for (int c = 0; c < nc; ++c) {
        boff[arr * 64 + c] = acc;
        acc += bsum[arr * 64 + c];
    }
    tot[arr] = acc;
}

// phase C: add chunk offsets, write cursor copy and rp[n]
__global__ __launch_bounds__(1024) void k_scanC(
    int* __restrict__ outB, int* __restrict__ curB, int nB_,
    int* __restrict__ outE, int* __restrict__ curE, int nE_,
    int* __restrict__ outX, int* __restrict__ curX, int nX_,
    const int* __restrict__ boff, const int* __restrict__ tot) {
    int arr = blockIdx.y;
    int* out = (arr == 0) ? outB : (arr == 1) ? outE : outX;
    int* cur = (arr == 0) ? curB : (arr == 1) ? curE : curX;
    int n = (arr == 0) ? nB_ : (arr == 1) ? nE_ : nX_;
    int chunk = blockIdx.x;
    if (chunk * 4096 >= n) return;
    int off = boff[arr * 64 + chunk];
    int tid = threadIdx.x;
    int base = chunk * 4096 + tid * 4;
#pragma unroll
    for (int j = 0; j < 4; ++j) {
        int i = base + j;
        if (i < n) {
            int v = out[i] + off;
            out[i] = v;
            cur[i] = v;
        }
    }
    if (chunk == 0 && tid == 0) out[n] = tot[arr];
}

__global__ void k_fill2(const int* __restrict__ dst, const int* __restrict__ src,
                        const float* __restrict__ w, int* __restrict__ cursor,
                        int* __restrict__ srcs_out, float* __restrict__ ws_out, int n) {
    int e = blockIdx.x * blockDim.x + threadIdx.x;
    if (e >= n) return;
    int p = atomicAdd(&cursor[dst[e]], 1);
    srcs_out[p] = src[e];
    ws_out[p] = w[e];
}

__global__ void k_fill1(const int* __restrict__ idx, int* __restrict__ cursor,
                        int* __restrict__ outm, int n) {
    int m = blockIdx.x * blockDim.x + threadIdx.x;
    if (m >= n) return;
    int p = atomicAdd(&cursor[idx[m]], 1);
    outm[p] = m;
}

// ---------------- fused MCE pull (4-edge MLP, R14-proven) ----------------
__global__ void k_pull_mce(const int* __restrict__ rp, const int* __restrict__ ivE,
                           const int* __restrict__ giE, const float* __restrict__ wE,
                           const u16* __restrict__ Pent, const u16* __restrict__ Prel,
                           u16* __restrict__ out, int ndst) {
    int wv = (blockIdx.x * blockDim.x + threadIdx.x) >> 6;
    if (wv >= ndst) return;
    int lane = threadIdx.x & 63;
    int beg = rp[wv], end = rp[wv + 1];
    float accA[2] = {0.f, 0.f}, accB[2] = {0.f, 0.f};
    int e = beg;
    for (; e + 4 <= end; e += 4) {
        int i0 = ivE[e], i1 = ivE[e + 1], i2 = ivE[e + 2], i3 = ivE[e + 3];
        int g0 = giE[e], g1 = giE[e + 1], g2 = giE[e + 2], g3 = giE[e + 3];
        float w0 = wE[e], w1 = wE[e + 1], w2 = wE[e + 2], w3 = wE[e + 3];
        const u32* pe0 = (const u32*)(Pent + (size_t)i0 * HH1);
        const u32* pe1 = (const u32*)(Pent + (size_t)i1 * HH1);
        const u32* pe2 = (const u32*)(Pent + (size_t)i2 * HH1);
        const u32* pe3 = (const u32*)(Pent + (size_t)i3 * HH1);
        const u32* pr0 = (const u32*)(Prel + (size_t)g0 * HH1);
        const u32* pr1 = (const u32*)(Prel + (size_t)g1 * HH1);
        const u32* pr2 = (const u32*)(Prel + (size_t)g2 * HH1);
        const u32* pr3 = (const u32*)(Prel + (size_t)g3 * HH1);
        u32 vp[4][2], vr[4][2];
#pragma unroll
        for (int t = 0; t < 2; ++t) {
            int p = lane + 64 * t;
            vp[0][t] = pe0[p]; vp[1][t] = pe1[p]; vp[2][t] = pe2[p]; vp[3][t] = pe3[p];
            vr[0][t] = pr0[p]; vr[1][t] = pr1[p]; vr[2][t] = pr2[p]; vr[3][t] = pr3[p];
        }
#pragma unroll
        for (int t = 0; t < 2; ++t) {
            float a, b, c, d;
            unpack2(vp[0][t], a, b); unpack2(vr[0][t], c, d);
            accA[t] += (a + c) * w0; accB[t] += (b + d) * w0;
            unpack2(vp[1][t], a, b); unpack2(vr[1][t], c, d);
            accA[t] += (a + c) * w1; accB[t] += (b + d) * w1;
            unpack2(vp[2][t], a, b); unpack2(vr[2][t], c, d);
            accA[t] += (a + c) * w2; accB[t] += (b + d) * w2;
            unpack2(vp[3][t], a, b); unpack2(vr[3][t], c, d);
            accA[t] += (a + c) * w3; accB[t] += (b + d) * w3;
        }
    }
    for (; e < end; ++e) {
        int iv = ivE[e], gi = giE[e];
        float w = wE[e];
        const u32* pe = (const u32*)(Pent + (size_t)iv * HH1);
        const u32* pr = (const u32*)(Prel + (size_t)gi * HH1);
#pragma unroll
        for (int t = 0; t < 2; ++t) {
            int p = lane + 64 * t;
            float a, b, c, d;
            unpack2(pe[p], a, b); unpack2(pr[p], c, d);
            accA[t] += (a + c) * w; accB[t] += (b + d) * w;
        }
    }
    u32* o = (u32*)(out + (size_t)wv * HH1);
#pragma unroll
    for (int t = 0; t < 2; ++t) o[lane + 64 * t] = pack2(accA[t], accB[t]);
}

// ---------------- CSR pull (4-edge MLP, R14-proven) ----------------
template<int DIMS, int INS, int OUTS>
__global__ void k_pull(const int* __restrict__ rp, const int* __restrict__ srcs,
                       const float* __restrict__ wsrt,
                       const u16* __restrict__ inh, const u16* __restrict__ inl,
                       u16* __restrict__ outh, u16* __restrict__ outl, int ndst) {
    int wv = (blockIdx.x * blockDim.x + threadIdx.x) >> 6;
    if (wv >= ndst) return;
    int lane = threadIdx.x & 63;
    int beg = rp[wv], end = rp[wv + 1];
    constexpr int NP = DIMS / 2;
    constexpr int NT = (NP + 63) / 64;
    float accA[NT], accB[NT];
#pragma unroll
    for (int t = 0; t < NT; ++t) { accA[t] = 0.f; accB[t] = 0.f; }
    int e = beg;
    for (; e + 4 <= end; e += 4) {
        int s0 = srcs[e], s1 = srcs[e + 1], s2 = srcs[e + 2], s3 = srcs[e + 3];
        float w0 = wsrt[e], w1 = wsrt[e + 1], w2 = wsrt[e + 2], w3 = wsrt[e + 3];
        const u32* rh[4] = {
            (const u32*)(inh + (size_t)s0 * DIMS), (const u32*)(inh + (size_t)s1 * DIMS),
            (const u32*)(inh + (size_t)s2 * DIMS), (const u32*)(inh + (size_t)s3 * DIMS)};
        u32 vh[4][NT], vl[4][NT];
#pragma unroll
        for (int t = 0; t < NT; ++t) {
            int p = lane + 64 * t;
            if (p < NP) {
                vh[0][t] = rh[0][p]; vh[1][t] = rh[1][p];
                vh[2][t] = rh[2][p]; vh[3][t] = rh[3][p];
            }
        }
        if (INS) {
            const u32* rl[4] = {
                (const u32*)(inl + (size_t)s0 * DIMS), (const u32*)(inl + (size_t)s1 * DIMS),
                (const u32*)(inl + (size_t)s2 * DIMS), (const u32*)(inl + (size_t)s3 * DIMS)};
#pragma unroll
            for (int t = 0; t < NT; ++t) {
                int p = lane + 64 * t;
                if (p < NP) {
                    vl[0][t] = rl[0][p]; vl[1][t] = rl[1][p];
                    vl[2][t] = rl[2][p]; vl[3][t] = rl[3][p];
                }
            }
        }
        float ws[4] = {w0, w1, w2, w3};
#pragma unroll
        for (int q = 0; q < 4; ++q) {
#pragma unroll
            for (int t = 0; t < NT; ++t) {
                int p = lane + 64 * t;
                if (p < NP) {
                    float a, b;
                    unpack2(vh[q][t], a, b);
                    if (INS) { float a2, b2; unpack2(vl[q][t], a2, b2); a += a2; b += b2; }
                    accA[t] += a * ws[q]; accB[t] += b * ws[q];
                }
            }
        }
    }
    for (; e < end; ++e) {
        int s = srcs[e];
        float w = wsrt[e];
        const u32* rh = (const u32*)(inh + (size_t)s * DIMS);
        const u32* rl = INS ? (const u32*)(inl + (size_t)s * DIMS) : nullptr;
#pragma unroll
        for (int t = 0; t < NT; ++t) {
            int p = lane + 64 * t;
            if (p < NP) {
                float a, b;
                unpack2(rh[p], a, b);
                if (INS) { float a2, b2; unpack2(rl[p], a2, b2); a += a2; b += b2; }
                accA[t] += a * w; accB[t] += b * w;
            }
        }
    }
    u32* oh = (u32*)(outh + (size_t)wv * DIMS);
    u32* ol = OUTS ? (u32*)(outl + (size_t)wv * DIMS) : nullptr;
#pragma unroll
    for (int t = 0; t < NT; ++t) {
        int p = lane + 64 * t;
        if (p < NP) {
            if (OUTS == 0) {
                oh[p] = pack2(accA[t], accB[t]);
            } else {
                u16 ha = f2bf(accA[t]), hb_ = f2bf(accB[t]);
                u16 la = f2bf(accA[t] - bf2f(ha)), lb = f2bf(accB[t] - bf2f(hb_));
                oh[p] = (u32)ha | ((u32)hb_ << 16);
                ol[p] = (u32)la | ((u32)lb << 16);
            }
        }
    }
}

// ---------------- fused segment mean + pooled ----------------
__global__ void k_segpool(const int* __restrict__ rpX, const int* __restrict__ mids,
                          const u16* __restrict__ e_buf, u16* __restrict__ pooled, int n) {
    int nv = (blockIdx.x * blockDim.x + threadIdx.x) >> 6;
    if (nv >= n) return;
    int lane = threadIdx.x & 63;
    int beg = rpX[nv], end = rpX[nv + 1];
    int cnt = end - beg;
    float accA[2] = {0.f, 0.f}, accB[2] = {0.f, 0.f};
    int e = beg;
    for (; e + 4 <= end; e += 4) {
        const u32* r0 = (const u32*)(e_buf + (size_t)mids[e] * DD);
        const u32* r1 = (const u32*)(e_buf + (size_t)mids[e + 1] * DD);
        const u32* r2 = (const u32*)(e_buf + (size_t)mids[e + 2] * DD);
        const u32* r3 = (const u32*)(e_buf + (size_t)mids[e + 3] * DD);
        u32 v[4][2];
#pragma unroll
        for (int t = 0; t < 2; ++t) {
            int p = lane + 64 * t;
            if (p < DD / 2) { v[0][t] = r0[p]; v[1][t] = r1[p]; v[2][t] = r2[p]; v[3][t] = r3[p]; }
        }
#pragma unroll
        for (int t = 0; t < 2; ++t) {
            int p = lane + 64 * t;
            if (p < DD / 2) {
                float a, b;
                unpack2(v[0][t], a, b); accA[t] += a; accB[t] += b;
                unpack2(v[1][t], a, b); accA[t] += a; accB[t] += b;
                unpack2(v[2][t], a, b); accA[t] += a; accB[t] += b;
                unpack2(v[3][t], a, b); accA[t] += a; accB[t] += b;
            }
        }
    }
    for (; e < end; ++e) {
        const u32* r = (const u32*)(e_buf + (size_t)mids[e] * DD);
#pragma unroll
        for (int t = 0; t < 2; ++t) {
            int p = lane + 64 * t;
            if (p < DD / 2) { float a, b; unpack2(r[p], a, b); accA[t] += a; accB[t] += b; }
        }
    }
    float inv = 1.0f / fmaxf((float)cnt, 1.0f);
    bool occ = cnt > 0;
    const u32* er = (const u32*)(e_buf + (size_t)nv * DD);
    u32* p0 = (u32*)(pooled + (size_t)nv * (2 * DD));
#pragma unroll
    for (int t = 0; t < 2; ++t) {
        int p = lane + 64 * t;
        if (p < DD / 2) {
            p0[p] = occ ? er[p] : 0u;
            p0[DD / 2 + p] = occ ? pack2(accA[t] * inv, accB[t] * inv) : 0u;
        }
    }
}

// ---------------- MFMA matmul, software-pipelined K-loop ----------------
template<int AMODE, int BLO, int RELU_IN, int RELU_OUT, int HAS_BIAS, int HAS_ADD, int FUSE, int CMODE>
__global__ __launch_bounds__(256) void k_mfmamm(
    const u16* __restrict__ Ah, const u16* __restrict__ Al,
    const u16* __restrict__ Bh, const u16* __restrict__ Bl,
    void* __restrict__ Cv, u16* __restrict__ Cl,
    int Mr, int Nc, int Kd, int redrows,
    const float* __restrict__ bias, const u16* __restrict__ addsrc,
    const int* __restrict__ addidx, const float* __restrict__ tvec,
    float* __restrict__ redout) {
    constexpr int BM = 128, BK = 32;
    constexpr int ASTR = 40;
    __shared__ u16 Ahs[2][BM * ASTR];
    __shared__ u16 Als[AMODE ? 2 : 1][AMODE ? (BM * ASTR) : 8];

    int tid = threadIdx.x;
    int wid = tid >> 6, lane = tid & 63;
    int wr = wid >> 1, wc = wid & 1;
    int r = lane & 15, h = lane >> 4;
    int bm0 = blockIdx.y * BM, bn0 = blockIdx.x * 128;
    int srow = (tid & 15) + 16 * (tid >> 6);
    int sg = (tid >> 4) & 3;
    int nk = (Kd + BK - 1) / BK;

    f32x4 acc[4][4];
#pragma unroll
    for (int i = 0; i < 4; ++i)
#pragma unroll
        for (int j = 0; j < 4; ++j) acc[i][j] = (f32x4){0.f, 0.f, 0.f, 0.f};

    uint4 pa[2], pl[2];
    {
        int kc = sg * 8;
        bool kok = (kc + 8 <= Kd);
#pragma unroll
        for (int it = 0; it < 2; ++it) {
            int row = srow + 64 * it;
            int gr = bm0 + row;
            uint4 v = make_uint4(0, 0, 0, 0), vl2 = make_uint4(0, 0, 0, 0);
            if (gr < Mr && kok) {
                v = *(const uint4*)(Ah + (size_t)gr * Kd + kc);
                if (AMODE) vl2 = *(const uint4*)(Al + (size_t)gr * Kd + kc);
            }
            if (RELU_IN) {
                v.x = relu2bf(v.x); v.y = relu2bf(v.y);
                v.z = relu2bf(v.z); v.w = relu2bf(v.w);
            }
            pa[it] = v;
            if (AMODE) pl[it] = vl2;
        }
#pragma unroll
        for (int it = 0; it < 2; ++it) {
            int row = srow + 64 * it;
            *(uint4*)(&Ahs[0][row * ASTR + sg * 8]) = pa[it];
            if (AMODE) *(uint4*)(&Als[0][row * ASTR + sg * 8]) = pl[it];
        }
    }
    __syncthreads();

    for (int k = 0; k < nk; ++k) {
        int cur = k & 1;
        uint4 na[2], nl[2];
        bool have_next = (k + 1 < nk);
        if (have_next) {
            int kc = (k + 1) * BK + sg * 8;
            bool kok = (kc + 8 <= Kd);
#pragma unroll
            for (int it = 0; it < 2; ++it) {
                int row = srow + 64 * it;
                int gr = bm0 + row;
                uint4 v = make_uint4(0, 0, 0, 0), vl2 = make_uint4(0, 0, 0, 0);
                if (gr < Mr && kok) {
                    v = *(const uint4*)(Ah + (size_t)gr * Kd + kc);
                    if (AMODE) vl2 = *(const uint4*)(Al + (size_t)gr * Kd + kc);
                }
                if (RELU_IN) {
                    v.x = relu2bf(v.x); v.y = relu2bf(v.y);
                    v.z = relu2bf(v.z); v.w = relu2bf(v.w);
                }
                na[it] = v;
                if (AMODE) nl[it] = vl2;
            }
        }
        bf16x8 bh4[4], bl4[4];
        {
            int kb = k * BK + h * 8;
            bool kbok = (kb + 8 <= Kd);
#pragma unroll
            for (int j = 0; j < 4; ++j) {
                int nrow = bn0 + wc * 64 + j * 16 + r;
                if (nrow < Nc && kbok) {
                    bh4[j] = *(const bf16x8*)(Bh + (size_t)nrow * Kd + kb);
                    if (BLO) bl4[j] = *(const bf16x8*)(Bl + (size_t)nrow * Kd + kb);
                } else { bh4[j] = zero8(); if (BLO) bl4[j] = zero8(); }
            }
        }
        bf16x8 af[4], alr[4];
#pragma unroll
        for (int i = 0; i < 4; ++i) {
            int mrow = wr * 64 + i * 16 + r;
            af[i] = *(const bf16x8*)(&Ahs[cur][mrow * ASTR + h * 8]);
            if (AMODE) alr[i] = *(const bf16x8*)(&Als[cur][mrow * ASTR + h * 8]);
        }
#pragma unroll
        for (int i = 0; i < 4; ++i)
#pragma unroll
            for (int j = 0; j < 4; ++j) {
                acc[i][j] = __builtin_amdgcn_mfma_f32_16x16x32_bf16(af[i], bh4[j], acc[i][j], 0, 0, 0);
                if (BLO)
                    acc[i][j] = __builtin_amdgcn_mfma_f32_16x16x32_bf16(af[i], bl4[j], acc[i][j], 0, 0, 0);
                if (AMODE)
                    acc[i][j] = __builtin_amdgcn_mfma_f32_16x16x32_bf16(alr[i], bh4[j], acc[i][j], 0, 0, 0);
            }
        if (have_next) {
#pragma unroll
            for (int it = 0; it < 2; ++it) {
                int row = srow + 64 * it;
                *(uint4*)(&Ahs[cur ^ 1][row * ASTR + sg * 8]) = na[it];
                if (AMODE) *(uint4*)(&Als[cur ^ 1][row * ASTR + sg * 8]) = nl[it];
            }
        }
        __syncthreads();
    }
    // ---- epilogue ----
    float colacc[4] = {0.f, 0.f, 0.f, 0.f};
#pragma unroll
    for (int i = 0; i < 4; ++i) {
        float rowacc[4] = {0.f, 0.f, 0.f, 0.f};
#pragma unroll
        for (int j = 0; j < 4; ++j) {
            int col = bn0 + wc * 64 + j * 16 + r;
            bool colok = col < Nc;
            float tv = (FUSE == 2 && colok) ? tvec[col] : 0.f;
#pragma unroll
            for (int rg = 0; rg < 4; ++rg) {
                int row = bm0 + wr * 64 + i * 16 + h * 4 + rg;
                float v = acc[i][j][rg];
                if (HAS_BIAS && colok) v += bias[col];
                if (RELU_OUT) v = fmaxf(v, 0.f);
                bool ok = colok && row < Mr;
                if (HAS_ADD && ok) {
                    int r2 = addidx ? addidx[row] : row;
                    v += bf2f(addsrc[(size_t)r2 * Nc + col]);
                }
                if (FUSE != 2 && ok) {
                    size_t cidx = (size_t)row * Nc + col;
                    if (CMODE == 0) ((u16*)Cv)[cidx] = f2bf(v);
                    else if (CMODE == 1) ((float*)Cv)[cidx] = v;
                    else {
                        u16 hi_ = f2bf(v);
                        ((u16*)Cv)[cidx] = hi_;
                        Cl[cidx] = f2bf(v - bf2f(hi_));
                    }
                }
                if (FUSE == 1 && ok && row < redrows) colacc[j] += v;
                if (FUSE == 2) rowacc[rg] += v * tv;
            }
        }
        if (FUSE == 2) {
#pragma unroll
            for (int rg = 0; rg < 4; ++rg) {
                float val = rowacc[rg];
                val += __shfl_xor(val, 1); val += __shfl_xor(val, 2);
                val += __shfl_xor(val, 4); val += __shfl_xor(val, 8);
                int row = bm0 + wr * 64 + i * 16 + h * 4 + rg;
                if (r == 0 && row < Mr) atomicAdd(&redout[row], val);
            }
        }
    }
    if (FUSE == 1) {
#pragma unroll
        for (int j = 0; j < 4; ++j) {
            float val = colacc[j];
            val += __shfl_xor(val, 16); val += __shfl_xor(val, 32);
            int col = bn0 + wc * 64 + j * 16 + r;
            if (h == 0 && col < Nc) atomicAdd(&redout[col], val);
        }
    }
}

// ---------------- DGI helpers ----------------
__global__ void k_tmv(const float* __restrict__ Wd, const float* __restrict__ csum,
                      float* __restrict__ tvec) {
    __shared__ float c[HIDD];
    int lane = threadIdx.x;
    for (int j = lane; j < HIDD; j += 64)
        c[j] = 1.0f / (1.0f + expf(-csum[j] * (1.0f / (float)NN)));
    __syncthreads();
    int r0 = blockIdx.x * 16;
    for (int i = r0; i < r0 + 16; ++i) {
        const float* wr = Wd + (size_t)i * HIDD;
        float s = 0.f;
        for (int j = lane; j < HIDD; j += 64) s += wr[j] * c[j];
        s = wredsum(s);
        if (lane == 0) tvec[i] = s;
    }
}

__global__ void k_rowdot512(const float* __restrict__ p, const float* __restrict__ t,
                            float* __restrict__ out, int rows) {
    int g = blockIdx.x * blockDim.x + threadIdx.x;
    int wv = g >> 6;
    if (wv >= rows) return;
    int lane = g & 63;
    const float* r = p + (size_t)wv * HIDD;
    float s = 0.f;
#pragma unroll
    for (int t4 = 0; t4 < 8; ++t4) {
        int d = lane + t4 * 64;
        s += r[d] * t[d];
    }
    s = wredsum(s);
    if (lane == 0) out[wv] = s;
}

__global__ void k_rowdot512b(const u16* __restrict__ p, const float* __restrict__ t,
                             float* __restrict__ out, int rows) {
    int g = blockIdx.x * blockDim.x + threadIdx.x;
    int wv = g >> 6;
    if (wv >= rows) return;
    int lane = g & 63;
    const u32* r = (const u32*)(p + (size_t)wv * HIDD);
    float s = 0.f;
#pragma unroll
    for (int t4 = 0; t4 < 4; ++t4) {
        int pp = lane + t4 * 64;
        float a, b;
        unpack2(r[pp], a, b);
        s += a * t[2 * pp] + b * t[2 * pp + 1];
    }
    s = wredsum(s);
    if (lane == 0) out[wv] = s;
}

// ---------------- ConvKB ----------------
__global__ void k_convkb(const u16* __restrict__ ec, const float* __restrict__ rel,
                         const int* __restrict__ bi, const float* __restrict__ cw,
                         const float* __restrict__ cb, const float* __restrict__ fcw,
                         const float* __restrict__ fcb, float* __restrict__ out) {
    __shared__ float t0[DD], t1[DD], t2[DD];
    __shared__ float red[4];
    int b = blockIdx.x, tid = threadIdx.x;
    int i0 = bi[b * 3 + 0], i1 = bi[b * 3 + 1], i2 = bi[b * 3 + 2];
    if (tid < DD) {
        t0[tid] = bf2f(ec[(size_t)i0 * DD + tid]);
        t1[tid] = rel[(size_t)i1 * DD + tid];
        t2[tid] = bf2f(ec[(size_t)i2 * DD + tid]);
    }
    __syncthreads();
    float partial = 0.f;
    if (tid < DD) {
        float a = t0[tid], bb = t1[tid], c = t2[tid];
        for (int o = 0; o < OCC; ++o) {
            float h = fmaxf(cw[o * 3 + 0] * a + cw[o * 3 + 1] * bb + cw[o * 3 + 2] * c + cb[o], 0.f);
            partial += h * fcw[o * DD + tid];
        }
    }
    partial = wredsum(partial);
    if ((tid & 63) == 0) red[tid >> 6] = partial;
    __syncthreads();
    if (tid == 0) out[b] = red[0] + red[1] + red[2] + red[3] + fcb[0];
}

__global__ void k_sentinel(float* out, float val) { out[threadIdx.x] = val; }

extern "C" void kernel_launch(void* const* d_in, const int* in_sizes, int n_in,
                              void* d_out, int out_size, void* d_ws, size_t ws_size,
                              hipStream_t stream) {
    const float* entity_emb = (const float*)d_in[0];
    const float* rel_emb    = (const float*)d_in[1];
    const int*   b_x        = (const int*)d_in[2];
    const int*   b_gi       = (const int*)d_in[3];
    const int*   e_src      = (const int*)d_in[4];
    const int*   e_dst      = (const int*)d_in[5];
    const float* e_w        = (const float*)d_in[6];
    const int*   big_src    = (const int*)d_in[7];
    const int*   big_dst    = (const int*)d_in[8];
    const float* big_w      = (const float*)d_in[9];
    const int*   perm       = (const int*)d_in[10];
    const int*   batch_in   = (const int*)d_in[11];
    const float* W1a        = (const float*)d_in[12];
    const float* W1b        = (const float*)d_in[13];
    const float* W2a        = (const float*)d_in[14];
    const float* W2b        = (const float*)d_in[15];
    // Wle/ble unused: segment softmax weights sum to exactly 1 and every row in a
    // segment shares the same emb vector -> pooled[n] == occ(n)*concat(e[n],mean[n])
    const float* Wlo        = (const float*)d_in[18];
    const float* blo        = (const float*)d_in[19];
    const float* Wg         = (const float*)d_in[20];
    const float* Wd         = (const float*)d_in[21];
    const float* conv_w     = (const float*)d_in[22];
    const float* conv_b     = (const float*)d_in[23];
    const float* fc_w       = (const float*)d_in[24];
    const float* fc_b       = (const float*)d_in[25];
    float* out = (float*)d_out;

    size_t off = 0;
    auto balloc = [&](size_t nbytes) {
        size_t p = off;
        off += (nbytes + 511) & ~(size_t)511;
        return p;
    };
    char* base = (char*)d_ws;
    u16*   entb = (u16*)(base + balloc((size_t)NN * DD * 2));
    float* relf = (float*)(base + balloc((size_t)RR * DD * 4));
    u16*   relb = (u16*)(base + balloc((size_t)RR * DD * 2));
    u16*   Pent = (u16*)(base + balloc((size_t)NN * HH1 * 2));
    u16*   Prel = (u16*)(base + balloc((size_t)RR * HH1 * 2));
    int*   idx1 = (int*)(base + balloc((size_t)MM * 4));
    int*   rpB  = (int*)(base + balloc((size_t)(NN + 1) * 4));
    int*   srcB = (int*)(base + balloc((size_t)NEE * 4));
    float* wB   = (float*)(base + balloc((size_t)NEE * 4));
    int*   rpE  = (int*)(base + balloc((size_t)(MM + 1) * 4));
    int*   srcE = (int*)(base + balloc((size_t)EE * 4));
    float* wE   = (float*)(base + balloc((size_t)EE * 4));
    int*   ivE  = (int*)(base + balloc((size_t)EE * 4));
    int*   giE  = (int*)(base + balloc((size_t)EE * 4));
    int*   rpX  = (int*)(base + balloc((size_t)(NN + 1) * 4));
    int*   mids = (int*)(base + balloc((size_t)MM * 4));
    int*   curB = (int*)(base + balloc((size_t)NN * 4));
    int*   curE = (int*)(base + balloc((size_t)MM * 4));
    int*   curX = (int*)(base + balloc((size_t)NN * 4));
    int*   bsum = (int*)(base + balloc(192 * 4));
    int*   boff = (int*)(base + balloc(192 * 4));
    int*   stot = (int*)(base + balloc(16 * 4));
    u16* w1aT_h  = (u16*)(base + balloc(200 * 256 * 2));
    u16* w1aT_l  = (u16*)(base + balloc(200 * 256 * 2));
    u16* w1abT_h = (u16*)(base + balloc(200 * 256 * 2));
    u16* w1abT_l = (u16*)(base + balloc(200 * 256 * 2));
    u16* w1bT_h  = (u16*)(base + balloc(256 * 200 * 2));
    u16* w1bT_l  = (u16*)(base + balloc(256 * 200 * 2));
    u16* wloT_h  = (u16*)(base + balloc(400 * 200 * 2));
    u16* wloT_l  = (u16*)(base + balloc(400 * 200 * 2));
    u16* wgT_h   = (u16*)(base + balloc(200 * 512 * 2));
    u16* wgT_l   = (u16*)(base + balloc(200 * 512 * 2));
    u16* w2aT_h  = (u16*)(base + balloc(200 * 256 * 2));
    u16* w2aT_l  = (u16*)(base + balloc(200 * 256 * 2));
    u16* w2bgT_h = (u16*)(base + balloc(512 * 256 * 2));
    u16* w2bgT_l = (u16*)(base + balloc(512 * 256 * 2));
    char*  Aarena = base + balloc((size_t)MM * HH1 * 2);   // 61.44 MB
    char*  Barena = base + balloc((size_t)MM * DD * 2);    // 48 MB
    char*  Carena = base + balloc((size_t)MM * DD * 2);    // 48 MB
    float* csum = (float*)(base + balloc(4 * 2048));
    float* cvec = csum + 512;
    float* t_l  = csum + 1024;
    float* t_g  = csum + 1536;
    // ecb LAST so an optional second plane can sit contiguously after it
    u16*   ecb  = (u16*)(base + balloc((size_t)NN * DD * 2));
    size_t off_small = off;
    u16*   ecb2 = ecb + (size_t)NN * DD;
    bool bigws = (off_small + (size_t)NN * DD * 2) <= ws_size;
    (void)cvec;

    if (ws_size < off_small) {
        k_sentinel<<<dim3(1), dim3(8), 0, stream>>>(out, (float)(ws_size >> 20));
        return;
    }

    const size_t PL = 20000000;   // 20 MB plane (NN*DD*2)
    const size_t PH = 25600000;   // 25.6 MB plane (NN*HH1*2)
    u16*   aggx   = (u16*)Aarena;                  // [MM,256] bf16
    u16*   hb     = (u16*)Barena;                  // [MM,200] bf16
    u16*   e_buf  = (u16*)Carena;                  // [MM,200] bf16
    u16*   pooled = (u16*)Aarena;                  // [NN,400] bf16
    u16*   a1h    = (u16*)Aarena;                  // [NN,200] split pair
    u16*   a1l    = (u16*)(Aarena + PL);
    u16*   h2h    = (u16*)Barena;                  // [NN,256] split pair (spans B..C)
    u16*   h2l    = (u16*)(Barena + PH);
    u16*   g2h    = (u16*)Aarena;                  // [NN,256] split pair (a1 dead)
    u16*   g2l    = (u16*)(Aarena + PH);
    u16*   pb16   = (u16*)Barena;                  // [NN,512] bf16 (global DGI v0)
    u16*   pb16L  = (u16*)Aarena;                  // [2NN,512] bf16 (merged local DGI, A..B)
    float* pbuf   = (float*)Aarena;                // [NN,512] f32 (small-path local DGI)

    dim3 blk(256);
    auto wgrid = [](int items) { return dim3((unsigned)((items + 3) / 4)); };
    auto tgrid = [](int items) { return dim3((unsigned)((items + 255) / 256)); };
    auto mmgrid = [](int Mr, int Nc) { return dim3((unsigned)((Nc + 127) / 128), (unsigned)((Mr + 127) / 128)); };

    // ---- normalize (merged) + perm gather + weight prep ----
    k_l2norm2<<<wgrid(NN + RR), blk, 0, stream>>>(entity_emb, rel_emb, entb, relf, relb);
    k_gather_perm<<<tgrid(MM), blk, 0, stream>>>(b_x, perm, idx1, MM);
    k_prepw<<<tgrid(256 * 200), blk, 0, stream>>>(W1a, 256, 200, w1aT_h, w1aT_l);
    k_prepw<<<tgrid(256 * 200), blk, 0, stream>>>(W1a + 200 * 256, 256, 200, w1abT_h, w1abT_l);
    k_prepw<<<tgrid(200 * 256), blk, 0, stream>>>(W1b, 200, 256, w1bT_h, w1bT_l);
    k_prepw<<<tgrid(200 * 400), blk, 0, stream>>>(Wlo, 200, 400, wloT_h, wloT_l);
    k_prepw<<<tgrid(512 * 200), blk, 0, stream>>>(Wg, 512, 200, wgT_h, wgT_l);
    k_prepw<<<tgrid(256 * 200), blk, 0, stream>>>(W2a, 256, 200, w2aT_h, w2aT_l);
    k_fusew<<<tgrid(512 * 256), blk, 0, stream>>>(W2b, Wg, w2bgT_h, w2bgT_l);

    // ---- CSR builds (merged hist, 3-phase multi-block scan) ----
    hipMemsetAsync(curB, 0, (size_t)NN * 4, stream);
    hipMemsetAsync(curE, 0, (size_t)MM * 4, stream);
    hipMemsetAsync(curX, 0, (size_t)NN * 4, stream);
    k_hist3<<<tgrid(NEE + EE + MM), blk, 0, stream>>>(big_dst, curB, NEE,
                                                      e_dst, curE, EE, b_x, curX, MM);
    {
        dim3 sgrid((unsigned)((MM + 4095) / 4096), 3);
        k_scanA<<<sgrid, dim3(1024), 0, stream>>>(curB, rpB, NN, curE, rpE, MM,
                                                  curX, rpX, NN, bsum);
        k_scanB<<<dim3(1), dim3(64), 0, stream>>>(bsum, boff, stot, NN, MM, NN);
        k_scanC<<<sgrid, dim3(1024), 0, stream>>>(rpB, curB, NN, rpE, curE, MM,
                                                  rpX, curX, NN, boff, stot);
    }
    k_fill2<<<tgrid(NEE), blk, 0, stream>>>(big_dst, big_src, big_w, curB, srcB, wB, NEE);
    k_fill2<<<tgrid(EE), blk, 0, stream>>>(e_dst, e_src, e_w, curE, srcE, wE, EE);
    k_fill1<<<tgrid(MM), blk, 0, stream>>>(b_x, curX, mids, MM);
    k_edge_idx<<<tgrid(EE), blk, 0, stream>>>(srcE, b_gi, giE, EE);

    // ---- P_ent / P_rel ----
    k_mfmamm<0, 0, 0, 0, 0, 0, 0, 0><<<mmgrid(NN, HH1), blk, 0, stream>>>(
        entb, nullptr, w1aT_h, w1aT_l, Pent, nullptr, NN, HH1, DD, NN,
        nullptr, nullptr, nullptr, nullptr, nullptr);
    k_mfmamm<0, 0, 0, 0, 0, 0, 0, 0><<<mmgrid(RR, HH1), blk, 0, stream>>>(
        relb, nullptr, w1abT_h, w1abT_l, Prel, nullptr, RR, HH1, DD, RR,
        nullptr, nullptr, nullptr, nullptr, nullptr);

    auto mce_pass = [&](int v, u16* ecdst) {
        const int* ivmap  = v ? idx1 : b_x;
        const int* addidx = v ? perm : nullptr;
        k_edge_idx<<<tgrid(EE), blk, 0, stream>>>(srcE, ivmap, ivE, EE);
        k_pull_mce<<<wgrid(MM), blk, 0, stream>>>(rpE, ivE, giE, wE, Pent, Prel, aggx, MM);
        k_mfmamm<0, 0, 1, 0, 0, 0, 0, 0><<<mmgrid(MM, DD), blk, 0, stream>>>(
            aggx, nullptr, w1bT_h, w1bT_l, hb, nullptr, MM, DD, HH1, MM,
            nullptr, nullptr, nullptr, nullptr, nullptr);
        k_pull<DD, 0, 0><<<wgrid(MM), blk, 0, stream>>>(rpE, srcE, wE, hb, nullptr,
                                                        e_buf, nullptr, MM);
        k_segpool<<<wgrid(NN), blk, 0, stream>>>(rpX, mids, e_buf, pooled, NN);
        k_mfmamm<0, 0, 0, 0, 1, 1, 0, 0><<<mmgrid(NN, DD), blk, 0, stream>>>(
            pooled, nullptr, wloT_h, wloT_l, ecdst, nullptr, NN, DD, 2 * DD, NN,
            blo, entb, addidx, nullptr, nullptr);
    };

    auto gcn_pass = [&](int v, const u16* ecsrc) {
        k_pull<DD, 0, 1><<<wgrid(NN), blk, 0, stream>>>(rpB, srcB, wB, ecsrc, nullptr,
                                                        a1h, a1l, NN);
        k_mfmamm<1, 1, 0, 1, 0, 0, 0, 2><<<mmgrid(NN, HH1), blk, 0, stream>>>(
            a1h, a1l, w2aT_h, w2aT_l, h2h, h2l, NN, HH1, DD, NN,
            nullptr, nullptr, nullptr, nullptr, nullptr);
        k_pull<HH1, 1, 1><<<wgrid(NN), blk, 0, stream>>>(rpB, srcB, wB, h2h, h2l,
                                                         g2h, g2l, NN);
        if (v == 0) {
            hipMemsetAsync(csum, 0, 512 * sizeof(float), stream);
            k_mfmamm<1, 1, 0, 1, 0, 0, 1, 0><<<mmgrid(NN, HIDD), blk, 0, stream>>>(
                g2h, g2l, w2bgT_h, w2bgT_l, pb16, nullptr, NN, HIDD, HH1, NN,
                nullptr, nullptr, nullptr, nullptr, csum);
            k_tmv<<<dim3(32), dim3(64), 0, stream>>>(Wd, csum, t_g);
            k_rowdot512b<<<wgrid(NN), blk, 0, stream>>>(pb16, t_g, out + BB + 2 * (size_t)NN, NN);
        } else {
            hipMemsetAsync(out + BB + 3 * (size_t)NN, 0, (size_t)NN * 4, stream);
            k_mfmamm<1, 1, 0, 1, 0, 0, 2, 0><<<mmgrid(NN, HIDD), blk, 0, stream>>>(
                g2h, g2l, w2bgT_h, w2bgT_l, nullptr, nullptr, NN, HIDD, HH1, NN,
                nullptr, nullptr, nullptr, t_g, out + BB + 3 * (size_t)NN);
        }
    };

    if (bigws) {
        mce_pass(0, ecb);
        mce_pass(1, ecb2);
        hipMemsetAsync(csum, 0, 512 * sizeof(float), stream);
        k_mfmamm<0, 0, 0, 1, 0, 0, 1, 0><<<mmgrid(2 * NN, HIDD), blk, 0, stream>>>(
            ecb, nullptr, wgT_h, wgT_l, pb16L, nullptr, 2 * NN, HIDD, DD, NN,
            nullptr, nullptr, nullptr, nullptr, csum);
        k_tmv<<<dim3(32), dim3(64), 0, stream>>>(Wd, csum, t_l);
        k_rowdot512b<<<wgrid(2 * NN), blk, 0, stream>>>(pb16L, t_l, out + BB, 2 * NN);
        k_convkb<<<dim3(BB), blk, 0, stream>>>(ecb, relf, batch_in,
                                               conv_w, conv_b, fc_w, fc_b, out);
        gcn_pass(0, ecb);
        gcn_pass(1, ecb2);
    } else {
        for (int v = 0; v < 2; ++v) {
            mce_pass(v, ecb);
            if (v == 0) {
                hipMemsetAsync(csum, 0, 512 * sizeof(float), stream);
                k_mfmamm<0, 0, 0, 1, 0, 0, 1, 1><<<mmgrid(NN, HIDD), blk, 0, stream>>>(
                    ecb, nullptr, wgT_h, wgT_l, pbuf, nullptr, NN, HIDD, DD, NN,
                    nullptr, nullptr, nullptr, nullptr, csum);
                k_tmv<<<dim3(32), dim3(64), 0, stream>>>(Wd, csum, t_l);
                k_rowdot512<<<wgrid(NN), blk, 0, stream>>>(pbuf, t_l, out + BB, NN);
                k_convkb<<<dim3(BB), blk, 0, stream>>>(ecb, relf, batch_in,
                                                       conv_w, conv_b, fc_w, fc_b, out);
            } else {
                hipMemsetAsync(out + BB + NN, 0, (size_t)NN * 4, stream);
                k_mfmamm<0, 0, 0, 1, 0, 0, 2, 1><<<mmgrid(NN, HIDD), blk, 0, stream>>>(
                    ecb, nullptr, wgT_h, wgT_l, nullptr, nullptr, NN, HIDD, DD, NN,
                    nullptr, nullptr, nullptr, t_l, out + BB + NN);
            }
            gcn_pass(v, ecb);
        }
    }

    (void)in_sizes; (void)n_in; (void)out_size;
}